// Round 1
// 317.017 us; speedup vs baseline: 1.0050x; 1.0050x over previous
//
#include <hip/hip_runtime.h>
#include <hip/hip_fp16.h>

constexpr int WPB = 4;   // waves per block
constexpr int TPW = 2;   // tokens per wave (software pipeline depth)

typedef int   v4i __attribute__((ext_vector_type(4)));
typedef unsigned int v4u __attribute__((ext_vector_type(4)));

// ---------- pre-pass: f32 codebooks -> fp16 (lossless, data was fp16) ------
__global__ __launch_bounds__(256) void cvt_kernel(
    const float* __restrict__ cb1, const float* __restrict__ cb2,
    unsigned int* __restrict__ o1, unsigned int* __restrict__ o2)
{
    const int r = blockIdx.x * 256 + threadIdx.x;        // 0..131071
    const float* src = (r < 65536) ? (cb1 + (size_t)r * 8)
                                   : (cb2 + (size_t)(r - 65536) * 8);
    unsigned int* dst = (r < 65536) ? (o1 + (size_t)r * 4)
                                    : (o2 + (size_t)(r - 65536) * 4);
    const float4 a = ((const float4*)src)[0];
    const float4 b = ((const float4*)src)[1];
    __half2 h0 = __floats2half2_rn(a.x, a.y);
    __half2 h1 = __floats2half2_rn(a.z, a.w);
    __half2 h2 = __floats2half2_rn(b.x, b.y);
    __half2 h3 = __floats2half2_rn(b.z, b.w);
    v4u o;
    o.x = *(unsigned int*)&h0; o.y = *(unsigned int*)&h1;
    o.z = *(unsigned int*)&h2; o.w = *(unsigned int*)&h3;
    *(v4u*)dst = o;
}

// ---------- helpers --------------------------------------------------------
// Issue all 8 codebook gathers (4 from each book) as one independent batch.
__device__ __forceinline__ void issue_gathers(const v4i q1, const v4i q2,
    const unsigned int* __restrict__ cb1h, const unsigned int* __restrict__ cb2h,
    v4u g1[4], v4u g2[4])
{
    const int i1[4] = { q1.x & 0xFFFF, q1.y & 0xFFFF, q1.z & 0xFFFF, q1.w & 0xFFFF };
    const int i2[4] = { q2.x & 0xFFFF, q2.y & 0xFFFF, q2.z & 0xFFFF, q2.w & 0xFFFF };
    #pragma unroll
    for (int c = 0; c < 4; ++c) g1[c] = *(const v4u*)(cb1h + (size_t)i1[c] * 4);
    #pragma unroll
    for (int c = 0; c < 4; ++c) g2[c] = *(const v4u*)(cb2h + (size_t)i2[c] * 4);
}

// fp16 pairs -> f32, combined with residual scale.
__device__ __forceinline__ void convert8(const v4u g1[4], const v4u g2[4],
    const float ws, const float ws2, float v[32])
{
    #pragma unroll
    for (int c = 0; c < 4; ++c) {
        const unsigned int au[4] = { g1[c].x, g1[c].y, g1[c].z, g1[c].w };
        const unsigned int bu[4] = { g2[c].x, g2[c].y, g2[c].z, g2[c].w };
        #pragma unroll
        for (int p = 0; p < 4; ++p) {
            const float2 fa = __half22float2(*(const __half2*)&au[p]);
            const float2 fb = __half22float2(*(const __half2*)&bu[p]);
            v[8*c + 2*p]     = fa.x * ws + fb.x * ws2;
            v[8*c + 2*p + 1] = fa.y * ws + fb.y * ws2;
        }
    }
}

// FHT(2048) + SV + store for one token. v[] holds combined/scaled inputs on
// entry (element e = lane*32 + r). L is this wave's private 8 KB LDS region.
__device__ __forceinline__ void process_tok(float v[32], float* __restrict__ L,
    const int lane, const float* __restrict__ SV, float* __restrict__ outp)
{
    // FHT bits 0..4 (within-thread)
    #pragma unroll
    for (int h = 1; h < 32; h <<= 1) {
        #pragma unroll
        for (int r = 0; r < 32; ++r) {
            if ((r & h) == 0) { float a = v[r], b = v[r + h]; v[r] = a + b; v[r + h] = a - b; }
        }
    }

    // Transposed LDS write (wave-private region, wave-synchronous).
    // col' = ((t>>2) ^ (j&15))*4 + (t&3): 2 lanes/bank, free.
    __builtin_amdgcn_wave_barrier();           // keep prior reads ahead of overwrite
    {
        const int t4 = lane >> 2, tl = lane & 3;
        #pragma unroll
        for (int j = 0; j < 32; ++j) {
            const int col = (((t4 ^ (j & 15)) << 2) | tl);
            L[(j << 6) + col] = v[j];
        }
    }
    __builtin_amdgcn_wave_barrier();           // pin ordering; lgkmcnt inserted by compiler

    // Phase 2: lane u = 2*j0 + b reads row j0, cols t = 32b..32b+31.
    const int j0 = lane >> 1;
    const int b  = lane & 1;
    float w[32];
    {
        const float4* Lr = (const float4*)(L + (j0 << 6));
        #pragma unroll
        for (int c = 0; c < 8; ++c) {
            const int ch = ((b << 3) + c) ^ (j0 & 15);
            const float4 f = Lr[ch];
            w[4*c + 0] = f.x; w[4*c + 1] = f.y; w[4*c + 2] = f.z; w[4*c + 3] = f.w;
        }
    }
    __builtin_amdgcn_wave_barrier();

    // SV prefetch: issue now, latency hides under the phase-2 FHT VALU work.
    const int ebase = (b << 10) | j0;
    float svv[32];
    #pragma unroll
    for (int r = 0; r < 32; ++r) svv[r] = SV[ebase + (r << 5)];

    // FHT bits 5..9 (within-thread)
    #pragma unroll
    for (int h = 1; h < 32; h <<= 1) {
        #pragma unroll
        for (int r = 0; r < 32; ++r) {
            if ((r & h) == 0) { float a = w[r], bb = w[r + h]; w[r] = a + bb; w[r + h] = a - bb; }
        }
    }

    // FHT bit 10: partner lane u^1 (quad_perm DPP)
    #pragma unroll
    for (int r = 0; r < 32; ++r) {
        const float o = __shfl_xor(w[r], 1, 64);
        w[r] = b ? (o - w[r]) : (w[r] + o);
    }

    // non-temporal f32 store: e = 1024*b + 32*r + j0 (coalesced per instr)
    #pragma unroll
    for (int r = 0; r < 32; ++r) {
        const int e = ebase + (r << 5);
        __builtin_nontemporal_store(w[r] * svv[r], &outp[e]);
    }
}

// ---------- main kernel: 2-token software pipeline per wave ----------------
__global__ __launch_bounds__(256, 4) void e8rht_kernel_h(
    const int* __restrict__ input_ids,
    const int* __restrict__ Qidxs,
    const int* __restrict__ Qidxs2,
    const unsigned int* __restrict__ cb1h,   // fp16 pairs: row = 4 uints (16 B)
    const unsigned int* __restrict__ cb2h,
    const float* __restrict__ SV,
    const float* __restrict__ Wscale,
    const float* __restrict__ inv_resid,
    float* __restrict__ out)
{
    __shared__ __align__(16) float lds[WPB * 2048];
    const int wave = threadIdx.x >> 6;
    const int lane = threadIdx.x & 63;
    const int tokA = (blockIdx.x * WPB + wave) * TPW;
    const int tokB = tokA + 1;

    const float ws  = Wscale[0];
    const float ws2 = ws * inv_resid[0];
    const int tidA = input_ids[tokA];        // wave-uniform -> s_load
    const int tidB = input_ids[tokB];

    // All 4 index-row loads in flight from the start (HBM latency paid once).
    // NT: streaming, keep L2 for codebooks.
    const v4i q1A = __builtin_nontemporal_load((const v4i*)(Qidxs  + (size_t)tidA * 256 + lane * 4));
    const v4i q2A = __builtin_nontemporal_load((const v4i*)(Qidxs2 + (size_t)tidA * 256 + lane * 4));
    const v4i q1B = __builtin_nontemporal_load((const v4i*)(Qidxs  + (size_t)tidB * 256 + lane * 4));
    const v4i q2B = __builtin_nontemporal_load((const v4i*)(Qidxs2 + (size_t)tidB * 256 + lane * 4));

    v4u g1[4], g2[4];
    float v[32];
    float* L = lds + wave * 2048;

    // Token A: gathers (full 8-wide batch), convert frees the g regs...
    issue_gathers(q1A, q2A, cb1h, cb2h, g1, g2);
    convert8(g1, g2, ws, ws2, v);
    // ...so token B's gathers fly during ALL of token A's FHT/LDS/store work.
    issue_gathers(q1B, q2B, cb1h, cb2h, g1, g2);
    process_tok(v, L, lane, SV, out + (size_t)tokA * 2048);

    // Token B: gathers should be long complete by now.
    convert8(g1, g2, ws, ws2, v);
    process_tok(v, L, lane, SV, out + (size_t)tokB * 2048);
}

// ---------- fallback (f32 gathers, 1 token/wave) — used if ws too small ----
__global__ __launch_bounds__(256, 4) void e8rht_kernel_f(
    const int* __restrict__ input_ids,
    const int* __restrict__ Qidxs,
    const int* __restrict__ Qidxs2,
    const float* __restrict__ codebook,
    const float* __restrict__ codebook2,
    const float* __restrict__ SV,
    const float* __restrict__ Wscale,
    const float* __restrict__ inv_resid,
    float* __restrict__ out)
{
    __shared__ __align__(16) float lds[WPB * 2048];
    const int wave = threadIdx.x >> 6;
    const int lane = threadIdx.x & 63;
    const int tok  = blockIdx.x * WPB + wave;

    const float ws  = Wscale[0];
    const float ws2 = ws * inv_resid[0];
    const int tid = input_ids[tok];

    const int4 q1 = *(const int4*)(Qidxs  + (size_t)tid * 256 + lane * 4);
    const int4 q2 = *(const int4*)(Qidxs2 + (size_t)tid * 256 + lane * 4);

    float v[32];
    {
        const int i1[4] = { q1.x & 0xFFFF, q1.y & 0xFFFF, q1.z & 0xFFFF, q1.w & 0xFFFF };
        const int i2[4] = { q2.x & 0xFFFF, q2.y & 0xFFFF, q2.z & 0xFFFF, q2.w & 0xFFFF };
        #pragma unroll
        for (int c = 0; c < 4; ++c) {
            const float4* r1 = (const float4*)(codebook  + (size_t)i1[c] * 8);
            const float4* r2 = (const float4*)(codebook2 + (size_t)i2[c] * 8);
            const float4 a0 = r1[0], a1 = r1[1];
            const float4 b0 = r2[0], b1 = r2[1];
            v[8*c+0]=a0.x*ws+b0.x*ws2; v[8*c+1]=a0.y*ws+b0.y*ws2;
            v[8*c+2]=a0.z*ws+b0.z*ws2; v[8*c+3]=a0.w*ws+b0.w*ws2;
            v[8*c+4]=a1.x*ws+b1.x*ws2; v[8*c+5]=a1.y*ws+b1.y*ws2;
            v[8*c+6]=a1.z*ws+b1.z*ws2; v[8*c+7]=a1.w*ws+b1.w*ws2;
        }
    }
    #pragma unroll
    for (int h = 1; h < 32; h <<= 1)
        #pragma unroll
        for (int r = 0; r < 32; ++r)
            if ((r & h) == 0) { float a=v[r],b=v[r+h]; v[r]=a+b; v[r+h]=a-b; }

    float* L = lds + wave * 2048;
    {
        const int t4 = lane >> 2, tl = lane & 3;
        #pragma unroll
        for (int j = 0; j < 32; ++j)
            L[(j << 6) + (((t4 ^ (j & 15)) << 2) | tl)] = v[j];
    }
    __syncthreads();
    const int j0 = lane >> 1;
    const int b  = lane & 1;
    float w[32];
    {
        const float4* Lr = (const float4*)(L + (j0 << 6));
        #pragma unroll
        for (int c = 0; c < 8; ++c) {
            const float4 f = Lr[((b << 3) + c) ^ (j0 & 15)];
            w[4*c+0]=f.x; w[4*c+1]=f.y; w[4*c+2]=f.z; w[4*c+3]=f.w;
        }
    }
    #pragma unroll
    for (int h = 1; h < 32; h <<= 1)
        #pragma unroll
        for (int r = 0; r < 32; ++r)
            if ((r & h) == 0) { float a=w[r],bb=w[r+h]; w[r]=a+bb; w[r+h]=a-bb; }
    #pragma unroll
    for (int r = 0; r < 32; ++r) {
        const float o = __shfl_xor(w[r], 1, 64);
        w[r] = b ? (o - w[r]) : (w[r] + o);
    }
    const size_t obase = (size_t)tok * 2048;
    const int ebase = (b << 10) | j0;
    #pragma unroll
    for (int r = 0; r < 32; ++r) {
        const int e = ebase + (r << 5);
        out[obase + e] = w[r] * SV[e];
    }
}

extern "C" void kernel_launch(void* const* d_in, const int* in_sizes, int n_in,
                              void* d_out, int out_size, void* d_ws, size_t ws_size,
                              hipStream_t stream) {
    const int* input_ids   = (const int*)d_in[0];
    const int* Qidxs       = (const int*)d_in[1];
    const int* Qidxs2      = (const int*)d_in[2];
    const float* codebook  = (const float*)d_in[3];
    const float* codebook2 = (const float*)d_in[4];
    const float* SV        = (const float*)d_in[5];
    const float* wscale    = (const float*)d_in[6];
    const float* irs       = (const float*)d_in[7];
    float* out             = (float*)d_out;

    const int n_tok = in_sizes[0];          // 16384

    const size_t cb_h_bytes = (size_t)65536 * 8 * 2;   // 1 MB per codebook
    if (ws_size >= 2 * cb_h_bytes) {
        unsigned int* cb1h = (unsigned int*)d_ws;
        unsigned int* cb2h = (unsigned int*)((char*)d_ws + cb_h_bytes);
        cvt_kernel<<<512, 256, 0, stream>>>(codebook, codebook2, cb1h, cb2h);
        const int grid = n_tok / (WPB * TPW);           // 2048 blocks
        e8rht_kernel_h<<<grid, 256, 0, stream>>>(input_ids, Qidxs, Qidxs2,
                                                 cb1h, cb2h, SV, wscale, irs, out);
    } else {
        const int grid = n_tok / WPB;                   // 4096 blocks
        e8rht_kernel_f<<<grid, 256, 0, stream>>>(input_ids, Qidxs, Qidxs2,
                                                 codebook, codebook2, SV,
                                                 wscale, irs, out);
    }
}

// Round 2
// 315.011 us; speedup vs baseline: 1.0114x; 1.0064x over previous
//
#include <hip/hip_runtime.h>
#include <hip/hip_fp16.h>

constexpr int WPB = 2;   // waves per block (main kernel)
constexpr int TPW = 2;   // tokens per wave (both tokens' gathers in flight)

typedef int   v4i __attribute__((ext_vector_type(4)));
typedef unsigned int v4u __attribute__((ext_vector_type(4)));

// ---------- pre-pass: f32 codebooks -> fp16 (lossless, data was fp16) ------
__global__ __launch_bounds__(256) void cvt_kernel(
    const float* __restrict__ cb1, const float* __restrict__ cb2,
    unsigned int* __restrict__ o1, unsigned int* __restrict__ o2)
{
    const int r = blockIdx.x * 256 + threadIdx.x;        // 0..131071
    const float* src = (r < 65536) ? (cb1 + (size_t)r * 8)
                                   : (cb2 + (size_t)(r - 65536) * 8);
    unsigned int* dst = (r < 65536) ? (o1 + (size_t)r * 4)
                                    : (o2 + (size_t)(r - 65536) * 4);
    const float4 a = ((const float4*)src)[0];
    const float4 b = ((const float4*)src)[1];
    __half2 h0 = __floats2half2_rn(a.x, a.y);
    __half2 h1 = __floats2half2_rn(a.z, a.w);
    __half2 h2 = __floats2half2_rn(b.x, b.y);
    __half2 h3 = __floats2half2_rn(b.z, b.w);
    v4u o;
    o.x = *(unsigned int*)&h0; o.y = *(unsigned int*)&h1;
    o.z = *(unsigned int*)&h2; o.w = *(unsigned int*)&h3;
    *(v4u*)dst = o;
}

// ---------- helpers --------------------------------------------------------
// Issue all 8 codebook gathers (4 from each book) as one independent batch.
__device__ __forceinline__ void issue_gathers(const v4i q1, const v4i q2,
    const unsigned int* __restrict__ cb1h, const unsigned int* __restrict__ cb2h,
    v4u g1[4], v4u g2[4])
{
    const int i1[4] = { q1.x & 0xFFFF, q1.y & 0xFFFF, q1.z & 0xFFFF, q1.w & 0xFFFF };
    const int i2[4] = { q2.x & 0xFFFF, q2.y & 0xFFFF, q2.z & 0xFFFF, q2.w & 0xFFFF };
    #pragma unroll
    for (int c = 0; c < 4; ++c) g1[c] = *(const v4u*)(cb1h + (size_t)i1[c] * 4);
    #pragma unroll
    for (int c = 0; c < 4; ++c) g2[c] = *(const v4u*)(cb2h + (size_t)i2[c] * 4);
}

// fp16 pairs -> f32, combined with residual scale.
__device__ __forceinline__ void convert8(const v4u g1[4], const v4u g2[4],
    const float ws, const float ws2, float v[32])
{
    #pragma unroll
    for (int c = 0; c < 4; ++c) {
        const unsigned int au[4] = { g1[c].x, g1[c].y, g1[c].z, g1[c].w };
        const unsigned int bu[4] = { g2[c].x, g2[c].y, g2[c].z, g2[c].w };
        #pragma unroll
        for (int p = 0; p < 4; ++p) {
            const float2 fa = __half22float2(*(const __half2*)&au[p]);
            const float2 fb = __half22float2(*(const __half2*)&bu[p]);
            v[8*c + 2*p]     = fa.x * ws + fb.x * ws2;
            v[8*c + 2*p + 1] = fa.y * ws + fb.y * ws2;
        }
    }
}

// FHT(2048) + SV + store for one token. v[] holds combined/scaled inputs on
// entry (element e = lane*32 + r). L is this wave's private 8 KB LDS region.
__device__ __forceinline__ void process_tok(float v[32], float* __restrict__ L,
    const int lane, const float* __restrict__ SV, float* __restrict__ outp)
{
    // FHT bits 0..4 (within-thread)
    #pragma unroll
    for (int h = 1; h < 32; h <<= 1) {
        #pragma unroll
        for (int r = 0; r < 32; ++r) {
            if ((r & h) == 0) { float a = v[r], b = v[r + h]; v[r] = a + b; v[r + h] = a - b; }
        }
    }

    // Transposed LDS write (wave-private region, wave-synchronous).
    // col' = ((t>>2) ^ (j&15))*4 + (t&3): 2 lanes/bank, free.
    __builtin_amdgcn_wave_barrier();           // keep prior reads ahead of overwrite
    {
        const int t4 = lane >> 2, tl = lane & 3;
        #pragma unroll
        for (int j = 0; j < 32; ++j) {
            const int col = (((t4 ^ (j & 15)) << 2) | tl);
            L[(j << 6) + col] = v[j];
        }
    }
    __builtin_amdgcn_wave_barrier();           // pin ordering; lgkmcnt inserted by compiler

    // Phase 2: lane u = 2*j0 + b reads row j0, cols t = 32b..32b+31.
    const int j0 = lane >> 1;
    const int b  = lane & 1;
    float w[32];
    {
        const float4* Lr = (const float4*)(L + (j0 << 6));
        #pragma unroll
        for (int c = 0; c < 8; ++c) {
            const int ch = ((b << 3) + c) ^ (j0 & 15);
            const float4 f = Lr[ch];
            w[4*c + 0] = f.x; w[4*c + 1] = f.y; w[4*c + 2] = f.z; w[4*c + 3] = f.w;
        }
    }
    __builtin_amdgcn_wave_barrier();

    // SV prefetch: issue now, latency hides under the phase-2 FHT VALU work.
    const int ebase = (b << 10) | j0;
    float svv[32];
    #pragma unroll
    for (int r = 0; r < 32; ++r) svv[r] = SV[ebase + (r << 5)];

    // FHT bits 5..9 (within-thread)
    #pragma unroll
    for (int h = 1; h < 32; h <<= 1) {
        #pragma unroll
        for (int r = 0; r < 32; ++r) {
            if ((r & h) == 0) { float a = w[r], bb = w[r + h]; w[r] = a + bb; w[r + h] = a - bb; }
        }
    }

    // FHT bit 10: partner lane u^1 (quad_perm DPP)
    #pragma unroll
    for (int r = 0; r < 32; ++r) {
        const float o = __shfl_xor(w[r], 1, 64);
        w[r] = b ? (o - w[r]) : (w[r] + o);
    }

    // non-temporal f32 store: e = 1024*b + 32*r + j0 (coalesced per instr)
    #pragma unroll
    for (int r = 0; r < 32; ++r) {
        const int e = ebase + (r << 5);
        __builtin_nontemporal_store(w[r] * svv[r], &outp[e]);
    }
}

// ---------- main kernel: both tokens' gathers in flight simultaneously -----
__global__ __launch_bounds__(128, 4) void e8rht_kernel_h(
    const int* __restrict__ input_ids,
    const int* __restrict__ Qidxs,
    const int* __restrict__ Qidxs2,
    const unsigned int* __restrict__ cb1h,   // fp16 pairs: row = 4 uints (16 B)
    const unsigned int* __restrict__ cb2h,
    const float* __restrict__ SV,
    const float* __restrict__ Wscale,
    const float* __restrict__ inv_resid,
    float* __restrict__ out)
{
    __shared__ __align__(16) float lds[WPB * 2048];    // 16 KB/block
    const int wave = threadIdx.x >> 6;
    const int lane = threadIdx.x & 63;
    const int tokA = (blockIdx.x * WPB + wave) * TPW;
    const int tokB = tokA + 1;

    const float ws  = Wscale[0];
    const float ws2 = ws * inv_resid[0];
    const int tidA = input_ids[tokA];        // wave-uniform -> s_load
    const int tidB = input_ids[tokB];

    // All 4 index-row loads in flight immediately (HBM latency paid once).
    // NT: streaming, keep L2 for codebooks.
    const v4i q1A = __builtin_nontemporal_load((const v4i*)(Qidxs  + (size_t)tidA * 256 + lane * 4));
    const v4i q2A = __builtin_nontemporal_load((const v4i*)(Qidxs2 + (size_t)tidA * 256 + lane * 4));
    const v4i q1B = __builtin_nontemporal_load((const v4i*)(Qidxs  + (size_t)tidB * 256 + lane * 4));
    const v4i q2B = __builtin_nontemporal_load((const v4i*)(Qidxs2 + (size_t)tidB * 256 + lane * 4));

    v4u gA1[4], gA2[4], gB1[4], gB2[4];
    float* L = lds + wave * 2048;

    // ALL 16 gather instructions (1024 line-misses/wave) issued back-to-back.
    issue_gathers(q1A, q2A, cb1h, cb2h, gA1, gA2);
    issue_gathers(q1B, q2B, cb1h, cb2h, gB1, gB2);
    // Pin: no load below may be sunk past this point; the 16 gathers above
    // stay issued before any compute. (Loads are memory ops; clobber orders.)
    asm volatile("" ::: "memory");

    float v[32];
    convert8(gA1, gA2, ws, ws2, v);          // compiler waits vmcnt(8): gB stays in flight
    process_tok(v, L, lane, SV, out + (size_t)tokA * 2048);

    convert8(gB1, gB2, ws, ws2, v);          // long complete by now
    process_tok(v, L, lane, SV, out + (size_t)tokB * 2048);
}

// ---------- fallback (f32 gathers, 1 token/wave) — used if ws too small ----
__global__ __launch_bounds__(256, 4) void e8rht_kernel_f(
    const int* __restrict__ input_ids,
    const int* __restrict__ Qidxs,
    const int* __restrict__ Qidxs2,
    const float* __restrict__ codebook,
    const float* __restrict__ codebook2,
    const float* __restrict__ SV,
    const float* __restrict__ Wscale,
    const float* __restrict__ inv_resid,
    float* __restrict__ out)
{
    __shared__ __align__(16) float lds[4 * 2048];
    const int wave = threadIdx.x >> 6;
    const int lane = threadIdx.x & 63;
    const int tok  = blockIdx.x * 4 + wave;

    const float ws  = Wscale[0];
    const float ws2 = ws * inv_resid[0];
    const int tid = input_ids[tok];

    const int4 q1 = *(const int4*)(Qidxs  + (size_t)tid * 256 + lane * 4);
    const int4 q2 = *(const int4*)(Qidxs2 + (size_t)tid * 256 + lane * 4);

    float v[32];
    {
        const int i1[4] = { q1.x & 0xFFFF, q1.y & 0xFFFF, q1.z & 0xFFFF, q1.w & 0xFFFF };
        const int i2[4] = { q2.x & 0xFFFF, q2.y & 0xFFFF, q2.z & 0xFFFF, q2.w & 0xFFFF };
        #pragma unroll
        for (int c = 0; c < 4; ++c) {
            const float4* r1 = (const float4*)(codebook  + (size_t)i1[c] * 8);
            const float4* r2 = (const float4*)(codebook2 + (size_t)i2[c] * 8);
            const float4 a0 = r1[0], a1 = r1[1];
            const float4 b0 = r2[0], b1 = r2[1];
            v[8*c+0]=a0.x*ws+b0.x*ws2; v[8*c+1]=a0.y*ws+b0.y*ws2;
            v[8*c+2]=a0.z*ws+b0.z*ws2; v[8*c+3]=a0.w*ws+b0.w*ws2;
            v[8*c+4]=a1.x*ws+b1.x*ws2; v[8*c+5]=a1.y*ws+b1.y*ws2;
            v[8*c+6]=a1.z*ws+b1.z*ws2; v[8*c+7]=a1.w*ws+b1.w*ws2;
        }
    }
    #pragma unroll
    for (int h = 1; h < 32; h <<= 1)
        #pragma unroll
        for (int r = 0; r < 32; ++r)
            if ((r & h) == 0) { float a=v[r],b=v[r+h]; v[r]=a+b; v[r+h]=a-b; }

    float* L = lds + wave * 2048;
    {
        const int t4 = lane >> 2, tl = lane & 3;
        #pragma unroll
        for (int j = 0; j < 32; ++j)
            L[(j << 6) + (((t4 ^ (j & 15)) << 2) | tl)] = v[j];
    }
    __syncthreads();
    const int j0 = lane >> 1;
    const int b  = lane & 1;
    float w[32];
    {
        const float4* Lr = (const float4*)(L + (j0 << 6));
        #pragma unroll
        for (int c = 0; c < 8; ++c) {
            const float4 f = Lr[((b << 3) + c) ^ (j0 & 15)];
            w[4*c+0]=f.x; w[4*c+1]=f.y; w[4*c+2]=f.z; w[4*c+3]=f.w;
        }
    }
    #pragma unroll
    for (int h = 1; h < 32; h <<= 1)
        #pragma unroll
        for (int r = 0; r < 32; ++r)
            if ((r & h) == 0) { float a=w[r],bb=w[r+h]; w[r]=a+bb; w[r+h]=a-bb; }
    #pragma unroll
    for (int r = 0; r < 32; ++r) {
        const float o = __shfl_xor(w[r], 1, 64);
        w[r] = b ? (o - w[r]) : (w[r] + o);
    }
    const size_t obase = (size_t)tok * 2048;
    const int ebase = (b << 10) | j0;
    #pragma unroll
    for (int r = 0; r < 32; ++r) {
        const int e = ebase + (r << 5);
        out[obase + e] = w[r] * SV[e];
    }
}

extern "C" void kernel_launch(void* const* d_in, const int* in_sizes, int n_in,
                              void* d_out, int out_size, void* d_ws, size_t ws_size,
                              hipStream_t stream) {
    const int* input_ids   = (const int*)d_in[0];
    const int* Qidxs       = (const int*)d_in[1];
    const int* Qidxs2      = (const int*)d_in[2];
    const float* codebook  = (const float*)d_in[3];
    const float* codebook2 = (const float*)d_in[4];
    const float* SV        = (const float*)d_in[5];
    const float* wscale    = (const float*)d_in[6];
    const float* irs       = (const float*)d_in[7];
    float* out             = (float*)d_out;

    const int n_tok = in_sizes[0];          // 16384

    const size_t cb_h_bytes = (size_t)65536 * 8 * 2;   // 1 MB per codebook
    if (ws_size >= 2 * cb_h_bytes) {
        unsigned int* cb1h = (unsigned int*)d_ws;
        unsigned int* cb2h = (unsigned int*)((char*)d_ws + cb_h_bytes);
        cvt_kernel<<<512, 256, 0, stream>>>(codebook, codebook2, cb1h, cb2h);
        const int grid = n_tok / (WPB * TPW);           // 4096 blocks of 128
        e8rht_kernel_h<<<grid, 128, 0, stream>>>(input_ids, Qidxs, Qidxs2,
                                                 cb1h, cb2h, SV, wscale, irs, out);
    } else {
        const int grid = n_tok / 4;                     // 4096 blocks of 256
        e8rht_kernel_f<<<grid, 256, 0, stream>>>(input_ids, Qidxs, Qidxs2,
                                                 codebook, codebook2, SV,
                                                 wscale, irs, out);
    }
}